// Round 1
// baseline (34.644 us; speedup 1.0000x reference)
//
#include <hip/hip_runtime.h>

// ESN scan: out[b,c,t,r] = s_t where s_t = tanh(x[b,c,t]*w[r] + s_{t-1}*d[r]).
// B=32 C=8 T=512 R=256. One block per (b,c), one thread per r-chain.
// Recurrence is sequential in t -> parallelism = 65536 lanes (4 waves/CU max).
// Memory floor: 128 MiB output write ~21 us @ 6.3 TB/s -> HBM-write-bound.

constexpr int Bdim = 32;
constexpr int Cdim = 8;
constexpr int Tdim = 512;
constexpr int Rdim = 256;

__device__ __forceinline__ float fast_exp2(float v) {
#if defined(__has_builtin)
#if __has_builtin(__builtin_amdgcn_exp2f)
    return __builtin_amdgcn_exp2f(v);
#else
    return exp2f(v);
#endif
#else
    return exp2f(v);
#endif
}

__global__ __launch_bounds__(256, 1) void esn_scan_kernel(
    const float* __restrict__ x,     // [B*C, T]
    const float* __restrict__ W_in,  // [R] (R,1 flattened)
    const float* __restrict__ d,     // [R]
    float* __restrict__ out)         // [B*C, T, R]
{
    const int bc = blockIdx.x;   // 0..255 : (b,c) pair
    const int r  = threadIdx.x;  // 0..255 : reservoir unit

    // Fold 2*log2(e) into the per-chain constants so that
    //   earg = s*dk + x*wk  ==  2*log2e*(s*d + x*w)
    //   tanh(a) = 1 - 2/(exp2(earg)+1)
    const float K  = 2.0f * 1.4426950408889634f;
    const float wk = W_in[r] * K;
    const float dk = d[r] * K;

    const float4* __restrict__ x4 = reinterpret_cast<const float4*>(x + bc * Tdim);
    float* __restrict__ o = out + (size_t)bc * Tdim * Rdim + r;

    float s = 0.0f;
    float4 cur = x4[0];

    #pragma unroll 1
    for (int t4 = 0; t4 < Tdim / 4; ++t4) {
        // Prefetch next group of 4 x-values (block-uniform broadcast load).
        const int nidx = (t4 + 1 < Tdim / 4) ? (t4 + 1) : t4;
        float4 nxt = x4[nidx];

        // Independent pre-multiplies (off the dependent chain).
        float xk0 = cur.x * wk;
        float xk1 = cur.y * wk;
        float xk2 = cur.z * wk;
        float xk3 = cur.w * wk;

        float* ob = o + (size_t)(t4 * 4) * Rdim;

        // Step 0
        {
            float earg = fmaf(s, dk, xk0);
            float e    = fast_exp2(earg);
            float rc   = __builtin_amdgcn_rcpf(e + 1.0f);
            s = fmaf(-2.0f, rc, 1.0f);
            ob[0 * Rdim] = s;
        }
        // Step 1
        {
            float earg = fmaf(s, dk, xk1);
            float e    = fast_exp2(earg);
            float rc   = __builtin_amdgcn_rcpf(e + 1.0f);
            s = fmaf(-2.0f, rc, 1.0f);
            ob[1 * Rdim] = s;
        }
        // Step 2
        {
            float earg = fmaf(s, dk, xk2);
            float e    = fast_exp2(earg);
            float rc   = __builtin_amdgcn_rcpf(e + 1.0f);
            s = fmaf(-2.0f, rc, 1.0f);
            ob[2 * Rdim] = s;
        }
        // Step 3
        {
            float earg = fmaf(s, dk, xk3);
            float e    = fast_exp2(earg);
            float rc   = __builtin_amdgcn_rcpf(e + 1.0f);
            s = fmaf(-2.0f, rc, 1.0f);
            ob[3 * Rdim] = s;
        }

        cur = nxt;
    }
}

extern "C" void kernel_launch(void* const* d_in, const int* in_sizes, int n_in,
                              void* d_out, int out_size, void* d_ws, size_t ws_size,
                              hipStream_t stream) {
    const float* x    = (const float*)d_in[0];  // [B,C,T]
    const float* W_in = (const float*)d_in[1];  // [R,1]
    const float* d    = (const float*)d_in[2];  // [R]
    float* out        = (float*)d_out;          // [B,C,T,R]

    dim3 grid(Bdim * Cdim);   // 256 blocks, one per (b,c)
    dim3 block(Rdim);         // 256 threads, one per r
    esn_scan_kernel<<<grid, block, 0, stream>>>(x, W_in, d, out);
}

// Round 2
// 26.732 us; speedup vs baseline: 1.2960x; 1.2960x over previous
//
#include <hip/hip_runtime.h>

// ESN scan: out[b,c,t,r] = s_t where s_t = tanh(x[b,c,t]*w[r] + s_{t-1}*d[r]).
// B=32 C=8 T=512 R=256. One block per (b,c), one thread per r-chain.
//
// R1 change: x row staged to LDS up front. The main loop previously issued a
// global load (x prefetch) between stores; consuming it forced s_waitcnt
// vmcnt(N), which (in-order retirement) drained the ENTIRE store queue every
// 4 steps (~500 cy). LDS reads use lgkmcnt -> stores are never waited on.

constexpr int Bdim = 32;
constexpr int Cdim = 8;
constexpr int Tdim = 512;
constexpr int Rdim = 256;

__device__ __forceinline__ float fast_exp2(float v) {
#if defined(__has_builtin)
#if __has_builtin(__builtin_amdgcn_exp2f)
    return __builtin_amdgcn_exp2f(v);
#else
    return exp2f(v);
#endif
#else
    return exp2f(v);
#endif
}

__global__ __launch_bounds__(256, 1) void esn_scan_kernel(
    const float* __restrict__ x,     // [B*C, T]
    const float* __restrict__ W_in,  // [R] (R,1 flattened)
    const float* __restrict__ d,     // [R]
    float* __restrict__ out)         // [B*C, T, R]
{
    const int bc = blockIdx.x;   // 0..255 : (b,c) pair
    const int r  = threadIdx.x;  // 0..255 : reservoir unit

    // tanh(a) = 1 - 2/(exp2(2*log2e*a)+1); fold 2*log2e into w,d.
    const float K  = 2.0f * 1.4426950408889634f;
    const float wk = W_in[r] * K;
    const float dk = d[r] * K;

    // Stage this block's x row (512 floats = 2 KiB) into LDS.
    __shared__ float4 xs4[Tdim / 4];   // 128 x float4
    {
        const float4* __restrict__ x4 = reinterpret_cast<const float4*>(x + bc * Tdim);
        if (threadIdx.x < Tdim / 4) {
            xs4[threadIdx.x] = x4[threadIdx.x];
        }
    }
    __syncthreads();

    float* __restrict__ o = out + (size_t)bc * Tdim * Rdim + r;

    float s = 0.0f;
    float4 cur = xs4[0];
    float4 nxt = xs4[1];

    #pragma unroll 1
    for (int t4 = 0; t4 < Tdim / 4; ++t4) {
        // 2-group-deep LDS prefetch (covers ~120 cy ds_read latency).
        const int fidx = (t4 + 2 < Tdim / 4) ? (t4 + 2) : (Tdim / 4 - 1);
        float4 fut = xs4[fidx];

        // Off-chain pre-multiplies.
        float xk0 = cur.x * wk;
        float xk1 = cur.y * wk;
        float xk2 = cur.z * wk;
        float xk3 = cur.w * wk;

        float* ob = o + (size_t)(t4 * 4) * Rdim;

        {   // Step 0
            float earg = fmaf(s, dk, xk0);
            float e    = fast_exp2(earg);
            float rc   = __builtin_amdgcn_rcpf(e + 1.0f);
            s = fmaf(-2.0f, rc, 1.0f);
            ob[0 * Rdim] = s;
        }
        {   // Step 1
            float earg = fmaf(s, dk, xk1);
            float e    = fast_exp2(earg);
            float rc   = __builtin_amdgcn_rcpf(e + 1.0f);
            s = fmaf(-2.0f, rc, 1.0f);
            ob[1 * Rdim] = s;
        }
        {   // Step 2
            float earg = fmaf(s, dk, xk2);
            float e    = fast_exp2(earg);
            float rc   = __builtin_amdgcn_rcpf(e + 1.0f);
            s = fmaf(-2.0f, rc, 1.0f);
            ob[2 * Rdim] = s;
        }
        {   // Step 3
            float earg = fmaf(s, dk, xk3);
            float e    = fast_exp2(earg);
            float rc   = __builtin_amdgcn_rcpf(e + 1.0f);
            s = fmaf(-2.0f, rc, 1.0f);
            ob[3 * Rdim] = s;
        }

        cur = nxt;
        nxt = fut;
    }
}

extern "C" void kernel_launch(void* const* d_in, const int* in_sizes, int n_in,
                              void* d_out, int out_size, void* d_ws, size_t ws_size,
                              hipStream_t stream) {
    const float* x    = (const float*)d_in[0];  // [B,C,T]
    const float* W_in = (const float*)d_in[1];  // [R,1]
    const float* d    = (const float*)d_in[2];  // [R]
    float* out        = (float*)d_out;          // [B,C,T,R]

    dim3 grid(Bdim * Cdim);   // 256 blocks, one per (b,c)
    dim3 block(Rdim);         // 256 threads, one per r
    esn_scan_kernel<<<grid, block, 0, stream>>>(x, W_in, d, out);
}